// Round 12
// baseline (22.383 us; speedup 1.0000x reference)
//
#include <hip/hip_runtime.h>
#include <math.h>

#define BB 2
#define LL 1024
#define DD 256
#define UU 32
#define RPB 4                   // rows per attn block
#define UNION (128 + RPB - 1)   // 131-row union band
#define TPB 1024
#define NGRP 8                  // phase-3 jru groups
#define NROW (BB * LL)
// prescale so tanh(v) = 1 - 2*rcp(exp2(SC*v)+1), SC = 2*log2(e)
#define SCALE 2.88539008177793f

// ---------------- qk: 8 rows/block, d-range halved per lane pair (h), 256 blocks x 512 thr ----------------
__global__ __launch_bounds__(512) void qk_kernel(
    const float* __restrict__ x, const float* __restrict__ Wt,
    const float* __restrict__ Wx, const float* __restrict__ bh,
    float* __restrict__ q, float* __restrict__ k)
{
    int t = threadIdx.x;
    int u = t & 31, h = (t >> 5) & 1, r = t >> 6;   // wave = (u:32, h:2), r wave-uniform
    int row = blockIdx.x * 8 + r;
    const float* xr = x + (size_t)row * DD + h * 128;
    const float* wt = Wt + (size_t)(h * 128) * UU + u;
    const float* wx = Wx + (size_t)(h * 128) * UU + u;
    float accq = 0.0f, acck = 0.0f;
    #pragma unroll 4
    for (int dq = 0; dq < 32; ++dq) {
        float4 xv = *(const float4*)(xr + dq * 4);   // broadcast float4 (was 4 scalar)
        accq = fmaf(xv.x, wt[(size_t)(dq * 4 + 0) * UU], accq);
        acck = fmaf(xv.x, wx[(size_t)(dq * 4 + 0) * UU], acck);
        accq = fmaf(xv.y, wt[(size_t)(dq * 4 + 1) * UU], accq);
        acck = fmaf(xv.y, wx[(size_t)(dq * 4 + 1) * UU], acck);
        accq = fmaf(xv.z, wt[(size_t)(dq * 4 + 2) * UU], accq);
        acck = fmaf(xv.z, wx[(size_t)(dq * 4 + 2) * UU], acck);
        accq = fmaf(xv.w, wt[(size_t)(dq * 4 + 3) * UU], accq);
        acck = fmaf(xv.w, wx[(size_t)(dq * 4 + 3) * UU], acck);
    }
    accq += __shfl_xor(accq, 32);                   // combine d-halves (h is lane bit 5)
    acck += __shfl_xor(acck, 32);
    if (h == 0) {
        q[(size_t)row * UU + u] = SCALE * accq;
        k[(size_t)row * UU + u] = SCALE * (acck + bh[u]);
    }
}

// ---------------- attn: 4 rows per 1024-thread block, 512 blocks (2/CU, 32 waves) ----------------
// Phase 1 is fully global-fed (ks band = 16 KB/block, L1-resident); LDS only for s_a4/s_part.
__global__ __launch_bounds__(TPB, 8) void attn_kernel(
    const float* __restrict__ x, const float* __restrict__ qs,
    const float* __restrict__ ks, const float* __restrict__ Wa,
    const float* __restrict__ ba, float* __restrict__ out)
{
    __shared__ float s_a4[(UNION + 1) * RPB];   // e-values, [jru][r], 16B rows
    __shared__ float s_c0;                      // ba + sum(Wa)
    __shared__ float s_inv[RPB];
    __shared__ float s_part[NGRP * RPB * DD];   // phase-3 group partials (32 KB)

    int t = threadIdx.x;
    int blk = blockIdx.x;
    int i0L = (blk * RPB) & (LL - 1);
    int b   = (blk * RPB) >> 10;
    int rowbase = blk * RPB;
    int j0L = i0L - 64;                          // union band start (local, signed)

    // ---- zero s_a4, compute c0 ----
    if (t < (UNION + 1) * RPB) s_a4[t] = 0.0f;
    if (t == 0) {
        float sw = ba[0];
        #pragma unroll
        for (int u = 0; u < UU; ++u) sw += Wa[u];
        s_c0 = sw;
    }
    __syncthreads();

    // ---- Phase 1: 512 e-entries, 2 threads each (16 u/thread); k/q/Wa from global (L1) ----
    {
        int entry = t >> 1, half = t & 1;
        int r = entry >> 7, jr = entry & 127;    // r wave-uniform
        int jru = r + jr;
        int jl = j0L + jru;                      // band condition == jl in [0,LL)
        float acc = 0.0f;
        if ((unsigned)jl < (unsigned)LL) {
            const float* kp = ks + (size_t)(b * LL + jl) * UU + half * 16;
            const float* qp = qs + (size_t)(rowbase + r) * UU + half * 16;
            const float* wp = Wa + half * 16;
            #pragma unroll
            for (int u = 0; u < 16; u += 4) {
                float4 k4 = *(const float4*)(kp + u);    // global b128, one base + imm offs
                float4 q4 = *(const float4*)(qp + u);    // wave-uniform broadcast
                float4 w4 = *(const float4*)(wp + u);    // block-uniform broadcast
                acc = fmaf(w4.x, __builtin_amdgcn_rcpf(__builtin_amdgcn_exp2f(q4.x + k4.x) + 1.0f), acc);
                acc = fmaf(w4.y, __builtin_amdgcn_rcpf(__builtin_amdgcn_exp2f(q4.y + k4.y) + 1.0f), acc);
                acc = fmaf(w4.z, __builtin_amdgcn_rcpf(__builtin_amdgcn_exp2f(q4.z + k4.z) + 1.0f), acc);
                acc = fmaf(w4.w, __builtin_amdgcn_rcpf(__builtin_amdgcn_exp2f(q4.w + k4.w) + 1.0f), acc);
            }
        }
        acc += __shfl_xor(acc, 1);               // pair shares same jl
        if (half == 0 && (unsigned)jl < (unsigned)LL)
            s_a4[jru * RPB + r] = __expf(fmaf(-2.0f, acc, s_c0));
    }
    __syncthreads();

    // ---- Phase 2 (waves 0-3): per-row denominators; s_inv read only after next barrier ----
    if (t < 4 * 64) {
        int r = t >> 6, lane = t & 63;
        float v = s_a4[lane * RPB + r] + s_a4[(lane + 64) * RPB + r];
        if (lane < UNION + 1 - 128) v += s_a4[(lane + 128) * RPB + r];
        #pragma unroll
        for (int off = 32; off > 0; off >>= 1) v += __shfl_xor(v, off);
        if (lane == 0) s_inv[r] = 1.0f / (v + 1e-7f);
    }

    // ---- Phase 3: thread (dq:64, rh:2, g:8); rh splits the d-range ----
    // Each x row is read exactly once per block (128 threads x float2 = 256 floats).
    {
        int dq = t & 63, rh = (t >> 6) & 1, g = t >> 7;
        int d0 = rh * 128 + dq * 2;
        float p00 = 0.f, p01 = 0.f, p10 = 0.f, p11 = 0.f;
        float p20 = 0.f, p21 = 0.f, p30 = 0.f, p31 = 0.f;
        const float* xb = x + (size_t)b * LL * DD + d0;
        for (int jru = g; jru < UNION; jru += NGRP) {
            int jl = j0L + jru;                  // wave-uniform guard
            if ((unsigned)jl < (unsigned)LL) {
                float2 xv = *(const float2*)(xb + (size_t)jl * DD);
                float4 e4 = *(const float4*)&s_a4[jru * RPB];   // uniform b128 broadcast
                p00 = fmaf(e4.x, xv.x, p00); p01 = fmaf(e4.x, xv.y, p01);
                p10 = fmaf(e4.y, xv.x, p10); p11 = fmaf(e4.y, xv.y, p11);
                p20 = fmaf(e4.z, xv.x, p20); p21 = fmaf(e4.z, xv.y, p21);
                p30 = fmaf(e4.w, xv.x, p30); p31 = fmaf(e4.w, xv.y, p31);
            }
        }
        *(float2*)&s_part[(g * RPB + 0) * DD + d0] = make_float2(p00, p01);
        *(float2*)&s_part[(g * RPB + 1) * DD + d0] = make_float2(p10, p11);
        *(float2*)&s_part[(g * RPB + 2) * DD + d0] = make_float2(p20, p21);
        *(float2*)&s_part[(g * RPB + 3) * DD + d0] = make_float2(p30, p31);
    }
    __syncthreads();

    // ---- Epilogue: reduce 8 group partials, normalize, store ----
    {
        int r = t >> 8, d = t & 255;
        float v = 0.0f;
        #pragma unroll
        for (int g = 0; g < NGRP; ++g)
            v += s_part[(g * RPB + r) * DD + d];
        out[(size_t)(rowbase + r) * DD + d] = v * s_inv[r];
    }
}

extern "C" void kernel_launch(void* const* d_in, const int* in_sizes, int n_in,
                              void* d_out, int out_size, void* d_ws, size_t ws_size,
                              hipStream_t stream) {
    const float* x  = (const float*)d_in[0];
    const float* Wt = (const float*)d_in[1];
    const float* Wx = (const float*)d_in[2];
    const float* bh = (const float*)d_in[3];
    const float* Wa = (const float*)d_in[4];
    const float* ba = (const float*)d_in[5];
    float* out = (float*)d_out;

    float* qs = (float*)d_ws;                     // [2048][32] prescaled q
    float* ks = qs + (size_t)NROW * UU;           // [2048][32] prescaled k (bias folded)

    qk_kernel<<<NROW / 8, 512, 0, stream>>>(x, Wt, Wx, bh, qs, ks);
    attn_kernel<<<NROW / RPB, TPB, 0, stream>>>(x, qs, ks, Wa, ba, out);
}

// Round 13
// 19.868 us; speedup vs baseline: 1.1266x; 1.1266x over previous
//
#include <hip/hip_runtime.h>
#include <math.h>

#define BB 2
#define LL 1024
#define DD 256
#define UU 32
#define RPB 4                   // rows per attn block
#define UNION (128 + RPB - 1)   // 131-row union band
#define KROW 36                 // padded LDS k row: b128-aligned, 2-way bank alias (free)
#define TPB 1024
#define NGRP 8                  // phase-3 jru groups
#define NROW (BB * LL)
// prescale so tanh(v) = 1 - 2*rcp(exp2(SC*v)+1), SC = 2*log2(e)
#define SCALE 2.88539008177793f

// ---------------- qk: 8 rows/block (1 row/wave), float4 W loads ----------------
// wave = (u4:8, dh:8): lane owns 4 u-columns x 32-d range; shfl-reduce over dh.
// 256 blocks x 512 thr; 64 W-loads + 8 x-loads per thread (vs 256 scalar W).
__global__ __launch_bounds__(512) void qk_kernel(
    const float* __restrict__ x, const float* __restrict__ Wt,
    const float* __restrict__ Wx, const float* __restrict__ bh,
    float* __restrict__ q, float* __restrict__ k)
{
    int t = threadIdx.x;
    int u4 = t & 7;             // 4-u group: u0 = u4*4
    int dh = (t >> 3) & 7;      // d-range eighth
    int r  = t >> 6;            // wave-uniform row
    int row = blockIdx.x * 8 + r;
    int u0 = u4 * 4;
    const float* xr  = x  + (size_t)row * DD + dh * 32;
    const float* wtp = Wt + (size_t)(dh * 32) * UU + u0;
    const float* wxp = Wx + (size_t)(dh * 32) * UU + u0;
    float q0=0.f,q1=0.f,q2=0.f,q3=0.f, k0=0.f,k1=0.f,k2=0.f,k3=0.f;
    #pragma unroll
    for (int dd = 0; dd < 32; dd += 4) {
        float4 xv = *(const float4*)(xr + dd);
        float4 w;
        w = *(const float4*)(wtp + (dd + 0) * UU);
        q0=fmaf(xv.x,w.x,q0); q1=fmaf(xv.x,w.y,q1); q2=fmaf(xv.x,w.z,q2); q3=fmaf(xv.x,w.w,q3);
        w = *(const float4*)(wxp + (dd + 0) * UU);
        k0=fmaf(xv.x,w.x,k0); k1=fmaf(xv.x,w.y,k1); k2=fmaf(xv.x,w.z,k2); k3=fmaf(xv.x,w.w,k3);
        w = *(const float4*)(wtp + (dd + 1) * UU);
        q0=fmaf(xv.y,w.x,q0); q1=fmaf(xv.y,w.y,q1); q2=fmaf(xv.y,w.z,q2); q3=fmaf(xv.y,w.w,q3);
        w = *(const float4*)(wxp + (dd + 1) * UU);
        k0=fmaf(xv.y,w.x,k0); k1=fmaf(xv.y,w.y,k1); k2=fmaf(xv.y,w.z,k2); k3=fmaf(xv.y,w.w,k3);
        w = *(const float4*)(wtp + (dd + 2) * UU);
        q0=fmaf(xv.z,w.x,q0); q1=fmaf(xv.z,w.y,q1); q2=fmaf(xv.z,w.z,q2); q3=fmaf(xv.z,w.w,q3);
        w = *(const float4*)(wxp + (dd + 2) * UU);
        k0=fmaf(xv.z,w.x,k0); k1=fmaf(xv.z,w.y,k1); k2=fmaf(xv.z,w.z,k2); k3=fmaf(xv.z,w.w,k3);
        w = *(const float4*)(wtp + (dd + 3) * UU);
        q0=fmaf(xv.w,w.x,q0); q1=fmaf(xv.w,w.y,q1); q2=fmaf(xv.w,w.z,q2); q3=fmaf(xv.w,w.w,q3);
        w = *(const float4*)(wxp + (dd + 3) * UU);
        k0=fmaf(xv.w,w.x,k0); k1=fmaf(xv.w,w.y,k1); k2=fmaf(xv.w,w.z,k2); k3=fmaf(xv.w,w.w,k3);
    }
    // reduce across dh (lane bits 3-5)
    #pragma unroll
    for (int off = 8; off < 64; off <<= 1) {
        q0 += __shfl_xor(q0, off); q1 += __shfl_xor(q1, off);
        q2 += __shfl_xor(q2, off); q3 += __shfl_xor(q3, off);
        k0 += __shfl_xor(k0, off); k1 += __shfl_xor(k1, off);
        k2 += __shfl_xor(k2, off); k3 += __shfl_xor(k3, off);
    }
    if (dh == 0) {
        *(float4*)(q + (size_t)row * UU + u0) =
            make_float4(SCALE*q0, SCALE*q1, SCALE*q2, SCALE*q3);
        const float4 bv = *(const float4*)(bh + u0);
        *(float4*)(k + (size_t)row * UU + u0) =
            make_float4(SCALE*(k0+bv.x), SCALE*(k1+bv.y), SCALE*(k2+bv.z), SCALE*(k3+bv.w));
    }
}

// ---------------- attn (R11 verbatim): 4 rows per 1024-thread block, 512 blocks ----------------
__global__ __launch_bounds__(TPB, 8) void attn_kernel(
    const float* __restrict__ x, const float* __restrict__ qs,
    const float* __restrict__ ks, const float* __restrict__ Wa,
    const float* __restrict__ ba, float* __restrict__ out)
{
    __shared__ float s_k[UNION * KROW];         // prescaled k band (18.9 KB)
    __shared__ float s_a4[(UNION + 1) * RPB];   // e-values, [jru][r], 16B rows
    __shared__ float s_q[RPB * UU];             // prescaled q
    __shared__ float s_wa[UU];
    __shared__ float s_c0;                      // ba + sum(Wa)
    __shared__ float s_inv[RPB];
    __shared__ float s_part[NGRP * RPB * DD];   // phase-3 group partials (32 KB)

    int t = threadIdx.x;
    int blk = blockIdx.x;
    int i0L = (blk * RPB) & (LL - 1);
    int b   = (blk * RPB) >> 10;
    int rowbase = blk * RPB;
    int j0L = i0L - 64;                          // union band start (local, signed)

    // ---- staging (all LDS-fed phase 1) ----
    if (t < RPB * UU) s_q[t] = qs[(size_t)rowbase * UU + t];
    if (t >= 128 && t < 128 + UU) s_wa[t - 128] = Wa[t - 128];
    if (t == 160) {
        float sw = ba[0];
        #pragma unroll
        for (int u = 0; u < UU; ++u) sw += Wa[u];
        s_c0 = sw;
    }
    if (t < (UNION + 1) * RPB) s_a4[t] = 0.0f;
    for (int idx = t; idx < UNION * 8; idx += TPB) {
        int jru = idx >> 3, uq = idx & 7;
        int jl = j0L + jru;
        if ((unsigned)jl < (unsigned)LL) {
            float4 kv = *(const float4*)(ks + (size_t)(b * LL + jl) * UU + uq * 4);
            *(float4*)&s_k[jru * KROW + uq * 4] = kv;
        }
    }
    __syncthreads();

    // ---- Phase 1: 512 e-entries, 2 threads each (16 u/thread), all-LDS operands ----
    {
        int entry = t >> 1, half = t & 1;
        int r = entry >> 7, jr = entry & 127;    // r wave-uniform
        int jru = r + jr;
        int jl = j0L + jru;                      // band condition == jl in [0,LL)
        float acc = 0.0f;
        if ((unsigned)jl < (unsigned)LL) {
            const float* kp = &s_k[jru * KROW + half * 16];
            const float* qp = &s_q[r * UU + half * 16];
            const float* wp = &s_wa[half * 16];
            #pragma unroll
            for (int u = 0; u < 16; u += 4) {
                float4 k4 = *(const float4*)(kp + u);    // ds_read_b128, 2-way alias
                float4 q4 = *(const float4*)(qp + u);    // LDS broadcast
                float4 w4 = *(const float4*)(wp + u);    // LDS broadcast
                acc = fmaf(w4.x, __builtin_amdgcn_rcpf(__builtin_amdgcn_exp2f(q4.x + k4.x) + 1.0f), acc);
                acc = fmaf(w4.y, __builtin_amdgcn_rcpf(__builtin_amdgcn_exp2f(q4.y + k4.y) + 1.0f), acc);
                acc = fmaf(w4.z, __builtin_amdgcn_rcpf(__builtin_amdgcn_exp2f(q4.z + k4.z) + 1.0f), acc);
                acc = fmaf(w4.w, __builtin_amdgcn_rcpf(__builtin_amdgcn_exp2f(q4.w + k4.w) + 1.0f), acc);
            }
        }
        acc += __shfl_xor(acc, 1);               // pair shares same jl
        if (half == 0 && (unsigned)jl < (unsigned)LL)
            s_a4[jru * RPB + r] = __expf(fmaf(-2.0f, acc, s_c0));
    }
    __syncthreads();

    // ---- Phase 2 (waves 0-3): per-row denominators; s_inv read only after next barrier ----
    if (t < 4 * 64) {
        int r = t >> 6, lane = t & 63;
        float v = s_a4[lane * RPB + r] + s_a4[(lane + 64) * RPB + r];
        if (lane < UNION + 1 - 128) v += s_a4[(lane + 128) * RPB + r];
        #pragma unroll
        for (int off = 32; off > 0; off >>= 1) v += __shfl_xor(v, off);
        if (lane == 0) s_inv[r] = 1.0f / (v + 1e-7f);
    }

    // ---- Phase 3: thread (dq:64, rh:2, g:8); rh splits the d-range ----
    {
        int dq = t & 63, rh = (t >> 6) & 1, g = t >> 7;
        int d0 = rh * 128 + dq * 2;
        float p00 = 0.f, p01 = 0.f, p10 = 0.f, p11 = 0.f;
        float p20 = 0.f, p21 = 0.f, p30 = 0.f, p31 = 0.f;
        const float* xb = x + (size_t)b * LL * DD + d0;
        for (int jru = g; jru < UNION; jru += NGRP) {
            int jl = j0L + jru;                  // wave-uniform guard
            if ((unsigned)jl < (unsigned)LL) {
                float2 xv = *(const float2*)(xb + (size_t)jl * DD);
                float4 e4 = *(const float4*)&s_a4[jru * RPB];   // uniform b128 broadcast
                p00 = fmaf(e4.x, xv.x, p00); p01 = fmaf(e4.x, xv.y, p01);
                p10 = fmaf(e4.y, xv.x, p10); p11 = fmaf(e4.y, xv.y, p11);
                p20 = fmaf(e4.z, xv.x, p20); p21 = fmaf(e4.z, xv.y, p21);
                p30 = fmaf(e4.w, xv.x, p30); p31 = fmaf(e4.w, xv.y, p31);
            }
        }
        *(float2*)&s_part[(g * RPB + 0) * DD + d0] = make_float2(p00, p01);
        *(float2*)&s_part[(g * RPB + 1) * DD + d0] = make_float2(p10, p11);
        *(float2*)&s_part[(g * RPB + 2) * DD + d0] = make_float2(p20, p21);
        *(float2*)&s_part[(g * RPB + 3) * DD + d0] = make_float2(p30, p31);
    }
    __syncthreads();

    // ---- Epilogue: reduce 8 group partials, normalize, store ----
    {
        int r = t >> 8, d = t & 255;
        float v = 0.0f;
        #pragma unroll
        for (int g = 0; g < NGRP; ++g)
            v += s_part[(g * RPB + r) * DD + d];
        out[(size_t)(rowbase + r) * DD + d] = v * s_inv[r];
    }
}

extern "C" void kernel_launch(void* const* d_in, const int* in_sizes, int n_in,
                              void* d_out, int out_size, void* d_ws, size_t ws_size,
                              hipStream_t stream) {
    const float* x  = (const float*)d_in[0];
    const float* Wt = (const float*)d_in[1];
    const float* Wx = (const float*)d_in[2];
    const float* bh = (const float*)d_in[3];
    const float* Wa = (const float*)d_in[4];
    const float* ba = (const float*)d_in[5];
    float* out = (float*)d_out;

    float* qs = (float*)d_ws;                     // [2048][32] prescaled q
    float* ks = qs + (size_t)NROW * UU;           // [2048][32] prescaled k (bias folded)

    qk_kernel<<<NROW / 8, 512, 0, stream>>>(x, Wt, Wx, bh, qs, ks);
    attn_kernel<<<NROW / RPB, TPB, 0, stream>>>(x, qs, ks, Wa, ba, out);
}

// Round 14
// 19.306 us; speedup vs baseline: 1.1594x; 1.0291x over previous
//
#include <hip/hip_runtime.h>
#include <math.h>

#define BB 2
#define LL 1024
#define DD 256
#define UU 32
#define RPB 4                   // rows per attn block
#define UNION (128 + RPB - 1)   // 131-row union band
#define KROW 36                 // padded LDS k row: b128-aligned, 2-way bank alias (free)
#define TPB 1024
#define NGRP 8                  // phase-3 jru groups
#define NROW (BB * LL)
// prescale so tanh(v) = 1 - 2*rcp(exp2(SC*v)+1), SC = 2*log2(e)
#define SCALE 2.88539008177793f

// ---------------- qk: emits Eq = exp2(SC*q), Ek = exp2(SC*(k+bh)) ----------------
// wave = (u4:8, dh:8): lane owns 4 u-columns x 32-d range; shfl-reduce over dh.
// 256 blocks x 512 thr; 64 float4 W-loads + 8 float4 x-loads per thread.
__global__ __launch_bounds__(512) void qk_kernel(
    const float* __restrict__ x, const float* __restrict__ Wt,
    const float* __restrict__ Wx, const float* __restrict__ bh,
    float* __restrict__ q, float* __restrict__ k)
{
    int t = threadIdx.x;
    int u4 = t & 7;             // 4-u group: u0 = u4*4
    int dh = (t >> 3) & 7;      // d-range eighth
    int r  = t >> 6;            // wave-uniform row
    int row = blockIdx.x * 8 + r;
    int u0 = u4 * 4;
    const float* xr  = x  + (size_t)row * DD + dh * 32;
    const float* wtp = Wt + (size_t)(dh * 32) * UU + u0;
    const float* wxp = Wx + (size_t)(dh * 32) * UU + u0;
    float q0=0.f,q1=0.f,q2=0.f,q3=0.f, k0=0.f,k1=0.f,k2=0.f,k3=0.f;
    #pragma unroll
    for (int dd = 0; dd < 32; dd += 4) {
        float4 xv = *(const float4*)(xr + dd);
        float4 w;
        w = *(const float4*)(wtp + (dd + 0) * UU);
        q0=fmaf(xv.x,w.x,q0); q1=fmaf(xv.x,w.y,q1); q2=fmaf(xv.x,w.z,q2); q3=fmaf(xv.x,w.w,q3);
        w = *(const float4*)(wxp + (dd + 0) * UU);
        k0=fmaf(xv.x,w.x,k0); k1=fmaf(xv.x,w.y,k1); k2=fmaf(xv.x,w.z,k2); k3=fmaf(xv.x,w.w,k3);
        w = *(const float4*)(wtp + (dd + 1) * UU);
        q0=fmaf(xv.y,w.x,q0); q1=fmaf(xv.y,w.y,q1); q2=fmaf(xv.y,w.z,q2); q3=fmaf(xv.y,w.w,q3);
        w = *(const float4*)(wxp + (dd + 1) * UU);
        k0=fmaf(xv.y,w.x,k0); k1=fmaf(xv.y,w.y,k1); k2=fmaf(xv.y,w.z,k2); k3=fmaf(xv.y,w.w,k3);
        w = *(const float4*)(wtp + (dd + 2) * UU);
        q0=fmaf(xv.z,w.x,q0); q1=fmaf(xv.z,w.y,q1); q2=fmaf(xv.z,w.z,q2); q3=fmaf(xv.z,w.w,q3);
        w = *(const float4*)(wxp + (dd + 2) * UU);
        k0=fmaf(xv.z,w.x,k0); k1=fmaf(xv.z,w.y,k1); k2=fmaf(xv.z,w.z,k2); k3=fmaf(xv.z,w.w,k3);
        w = *(const float4*)(wtp + (dd + 3) * UU);
        q0=fmaf(xv.w,w.x,q0); q1=fmaf(xv.w,w.y,q1); q2=fmaf(xv.w,w.z,q2); q3=fmaf(xv.w,w.w,q3);
        w = *(const float4*)(wxp + (dd + 3) * UU);
        k0=fmaf(xv.w,w.x,k0); k1=fmaf(xv.w,w.y,k1); k2=fmaf(xv.w,w.z,k2); k3=fmaf(xv.w,w.w,k3);
    }
    // reduce across dh (lane bits 3-5)
    #pragma unroll
    for (int off = 8; off < 64; off <<= 1) {
        q0 += __shfl_xor(q0, off); q1 += __shfl_xor(q1, off);
        q2 += __shfl_xor(q2, off); q3 += __shfl_xor(q3, off);
        k0 += __shfl_xor(k0, off); k1 += __shfl_xor(k1, off);
        k2 += __shfl_xor(k2, off); k3 += __shfl_xor(k3, off);
    }
    if (dh == 0) {
        *(float4*)(q + (size_t)row * UU + u0) = make_float4(
            __builtin_amdgcn_exp2f(SCALE * q0), __builtin_amdgcn_exp2f(SCALE * q1),
            __builtin_amdgcn_exp2f(SCALE * q2), __builtin_amdgcn_exp2f(SCALE * q3));
        const float4 bv = *(const float4*)(bh + u0);
        *(float4*)(k + (size_t)row * UU + u0) = make_float4(
            __builtin_amdgcn_exp2f(SCALE * (k0 + bv.x)), __builtin_amdgcn_exp2f(SCALE * (k1 + bv.y)),
            __builtin_amdgcn_exp2f(SCALE * (k2 + bv.z)), __builtin_amdgcn_exp2f(SCALE * (k3 + bv.w)));
    }
}

// ---------------- attn: 4 rows per 1024-thread block, 512 blocks (2/CU, 32 waves) ----------------
__global__ __launch_bounds__(TPB, 8) void attn_kernel(
    const float* __restrict__ x, const float* __restrict__ qs,
    const float* __restrict__ ks, const float* __restrict__ Wa,
    const float* __restrict__ ba, float* __restrict__ out)
{
    __shared__ float s_k[UNION * KROW];         // Ek band (18.9 KB)
    __shared__ float s_a4[(UNION + 1) * RPB];   // e-values, [jru][r], 16B rows
    __shared__ float s_q[RPB * UU];             // Eq
    __shared__ float s_wa[UU];
    __shared__ float s_c0;                      // ba + sum(Wa)
    __shared__ float s_inv[RPB];
    __shared__ float s_part[NGRP * RPB * DD];   // phase-3 group partials (32 KB)

    int t = threadIdx.x;
    int blk = blockIdx.x;
    int i0L = (blk * RPB) & (LL - 1);
    int b   = (blk * RPB) >> 10;
    int rowbase = blk * RPB;
    int j0L = i0L - 64;                          // union band start (local, signed)

    // ---- staging (all LDS-fed phase 1) ----
    if (t < RPB * UU) s_q[t] = qs[(size_t)rowbase * UU + t];
    if (t >= 128 && t < 128 + UU) s_wa[t - 128] = Wa[t - 128];
    if (t == 160) {
        float sw = ba[0];
        #pragma unroll
        for (int u = 0; u < UU; ++u) sw += Wa[u];
        s_c0 = sw;
    }
    if (t < (UNION + 1) * RPB) s_a4[t] = 0.0f;
    for (int idx = t; idx < UNION * 8; idx += TPB) {
        int jru = idx >> 3, uq = idx & 7;
        int jl = j0L + jru;
        if ((unsigned)jl < (unsigned)LL) {
            float4 kv = *(const float4*)(ks + (size_t)(b * LL + jl) * UU + uq * 4);
            *(float4*)&s_k[jru * KROW + uq * 4] = kv;
        }
    }
    __syncthreads();

    // ---- Phase 1: 512 e-entries, 2 threads each (16 u/thread), all-LDS operands ----
    // tanh term: 1 - 2*rcp(Eq*Ek + 1)  (one fma replaces add+exp2)
    {
        int entry = t >> 1, half = t & 1;
        int r = entry >> 7, jr = entry & 127;    // r wave-uniform
        int jru = r + jr;
        int jl = j0L + jru;                      // band condition == jl in [0,LL)
        float acc = 0.0f;
        if ((unsigned)jl < (unsigned)LL) {
            const float* kp = &s_k[jru * KROW + half * 16];
            const float* qp = &s_q[r * UU + half * 16];
            const float* wp = &s_wa[half * 16];
            #pragma unroll
            for (int u = 0; u < 16; u += 4) {
                float4 k4 = *(const float4*)(kp + u);    // ds_read_b128, 2-way alias
                float4 q4 = *(const float4*)(qp + u);    // LDS broadcast
                float4 w4 = *(const float4*)(wp + u);    // LDS broadcast
                acc = fmaf(w4.x, __builtin_amdgcn_rcpf(fmaf(q4.x, k4.x, 1.0f)), acc);
                acc = fmaf(w4.y, __builtin_amdgcn_rcpf(fmaf(q4.y, k4.y, 1.0f)), acc);
                acc = fmaf(w4.z, __builtin_amdgcn_rcpf(fmaf(q4.z, k4.z, 1.0f)), acc);
                acc = fmaf(w4.w, __builtin_amdgcn_rcpf(fmaf(q4.w, k4.w, 1.0f)), acc);
            }
        }
        acc += __shfl_xor(acc, 1);               // pair shares same jl
        if (half == 0 && (unsigned)jl < (unsigned)LL)
            s_a4[jru * RPB + r] = __expf(fmaf(-2.0f, acc, s_c0));
    }
    __syncthreads();

    // ---- Phase 2 (waves 0-3): per-row denominators; s_inv read only after next barrier ----
    if (t < 4 * 64) {
        int r = t >> 6, lane = t & 63;
        float v = s_a4[lane * RPB + r] + s_a4[(lane + 64) * RPB + r];
        if (lane < UNION + 1 - 128) v += s_a4[(lane + 128) * RPB + r];
        #pragma unroll
        for (int off = 32; off > 0; off >>= 1) v += __shfl_xor(v, off);
        if (lane == 0) s_inv[r] = 1.0f / (v + 1e-7f);
    }

    // ---- Phase 3: thread (dq:64, rh:2, g:8); rh splits the d-range ----
    {
        int dq = t & 63, rh = (t >> 6) & 1, g = t >> 7;
        int d0 = rh * 128 + dq * 2;
        float p00 = 0.f, p01 = 0.f, p10 = 0.f, p11 = 0.f;
        float p20 = 0.f, p21 = 0.f, p30 = 0.f, p31 = 0.f;
        const float* xb = x + (size_t)b * LL * DD + d0;
        for (int jru = g; jru < UNION; jru += NGRP) {
            int jl = j0L + jru;                  // wave-uniform guard
            if ((unsigned)jl < (unsigned)LL) {
                float2 xv = *(const float2*)(xb + (size_t)jl * DD);
                float4 e4 = *(const float4*)&s_a4[jru * RPB];   // uniform b128 broadcast
                p00 = fmaf(e4.x, xv.x, p00); p01 = fmaf(e4.x, xv.y, p01);
                p10 = fmaf(e4.y, xv.x, p10); p11 = fmaf(e4.y, xv.y, p11);
                p20 = fmaf(e4.z, xv.x, p20); p21 = fmaf(e4.z, xv.y, p21);
                p30 = fmaf(e4.w, xv.x, p30); p31 = fmaf(e4.w, xv.y, p31);
            }
        }
        *(float2*)&s_part[(g * RPB + 0) * DD + d0] = make_float2(p00, p01);
        *(float2*)&s_part[(g * RPB + 1) * DD + d0] = make_float2(p10, p11);
        *(float2*)&s_part[(g * RPB + 2) * DD + d0] = make_float2(p20, p21);
        *(float2*)&s_part[(g * RPB + 3) * DD + d0] = make_float2(p30, p31);
    }
    __syncthreads();

    // ---- Epilogue: reduce 8 group partials, normalize, store ----
    {
        int r = t >> 8, d = t & 255;
        float v = 0.0f;
        #pragma unroll
        for (int g = 0; g < NGRP; ++g)
            v += s_part[(g * RPB + r) * DD + d];
        out[(size_t)(rowbase + r) * DD + d] = v * s_inv[r];
    }
}

extern "C" void kernel_launch(void* const* d_in, const int* in_sizes, int n_in,
                              void* d_out, int out_size, void* d_ws, size_t ws_size,
                              hipStream_t stream) {
    const float* x  = (const float*)d_in[0];
    const float* Wt = (const float*)d_in[1];
    const float* Wx = (const float*)d_in[2];
    const float* bh = (const float*)d_in[3];
    const float* Wa = (const float*)d_in[4];
    const float* ba = (const float*)d_in[5];
    float* out = (float*)d_out;

    float* qs = (float*)d_ws;                     // [2048][32] Eq = exp2(SC*q)
    float* ks = qs + (size_t)NROW * UU;           // [2048][32] Ek = exp2(SC*(k+bh))

    qk_kernel<<<NROW / 8, 512, 0, stream>>>(x, Wt, Wx, bh, qs, ks);
    attn_kernel<<<NROW / RPB, TPB, 0, stream>>>(x, qs, ks, Wa, ba, out);
}